// Round 16
// baseline (538.900 us; speedup 1.0000x reference)
//
#include <hip/hip_runtime.h>
#include <hip/hip_bf16.h>

#define NE 64
#define HDIM 1024
#define FDIM 2048
#define TDIM 16384

typedef __attribute__((ext_vector_type(8))) short short8;
typedef __attribute__((ext_vector_type(4))) float f32x4;
typedef unsigned short u16;
typedef unsigned int u32;

struct IC0 { static constexpr int v = 0; };
struct IC1 { static constexpr int v = 1; };

__device__ __forceinline__ u16 f2bf(float f) {
  return __bfloat16_as_ushort(__float2bfloat16(f));
}
__device__ __forceinline__ u32 pk2(float a, float b) {
  return (u32)f2bf(a) | ((u32)f2bf(b) << 16);
}
__device__ __forceinline__ float gelu_tanh(float x) {
  float y = 0.7978845608f * (x + 0.044715f * x * x * x);
  float e = exp2f(2.885390082f * y);          // e^{2y}; inf/0 at extremes -> exact +-1
  float th = 1.f - 2.f / (e + 1.f);
  return 0.5f * x * (1.f + th);
}
template<int N> __device__ __forceinline__ void waitv() {
  if constexpr (N == 2)       asm volatile("s_waitcnt vmcnt(2)" ::: "memory");
  else if constexpr (N == 4)  asm volatile("s_waitcnt vmcnt(4)" ::: "memory");
  else if constexpr (N == 6)  asm volatile("s_waitcnt vmcnt(6)" ::: "memory");
  else if constexpr (N == 8)  asm volatile("s_waitcnt vmcnt(8)" ::: "memory");
  else if constexpr (N == 10) asm volatile("s_waitcnt vmcnt(10)" ::: "memory");
}
__device__ __forceinline__ void waitl() {
  asm volatile("s_waitcnt lgkmcnt(0)" ::: "memory");
}

// ---- prep: build M-block map (expert, row0, rowend), BM=256 ----
__global__ void k_prep(const int* __restrict__ tpe, int4* __restrict__ map,
                       int* __restrict__ nblocks) {
  if (threadIdx.x != 0 || blockIdx.x != 0) return;
  int off = 0, nb = 0;
  for (int e = 0; e < NE; ++e) {
    int n = tpe[e];
    for (int r = 0; r < n; r += 256) {
      int re = (r + 256 < n) ? (r + 256) : n;
      map[nb++] = make_int4(e, off + r, off + re, 0);
    }
    off += n;
  }
  *nblocks = nb;
}

// ---- x f32 -> bf16 ----
__global__ void k_conv(const float4* __restrict__ in, uint2* __restrict__ out, int n4) {
  int stride = gridDim.x * blockDim.x;
  for (int i = blockIdx.x * blockDim.x + threadIdx.x; i < n4; i += stride) {
    float4 v = in[i];
    uint2 o;
    o.x = pk2(v.x, v.y);
    o.y = pk2(v.z, v.w);
    out[i] = o;
  }
}

// ======================= GEMM1: h = gelu(x @ w1^T) =======================
// m201-style 4-phase schedule. 256x256 tile, BK=64, 512 thr = 8 waves (2Mx4N),
// wave-tile 128x64, acc[8][4]. Per tile: 4 phases (mhalf x kslice), each:
//   [vmcnt-wait][ds_reads][stage/load issues][writeB chunk][BAR][lgkm0]
//   [setprio1  16 MFMA  setprio0][BAR]
// A: bf16 gload_lds into sa[2] ([256][64], 8x16B chunks XOR-swz j^(r&7) both
//    sides -> 2-way max on frag reads). All 4 issues in ph0, 1-tile flight.
// B: w1 f32 [N][K] -> 8x float4/thread/tile in 4 chunks (2/phase, 1-tile-flight
//    reg sets ping-pong) -> pk2 -> ds_write into sb[2] [256 n][72 u16] (144B
//    pitch: rows cycle banks, 2-way max).
// Steady queue at tile t ph0 (oldest first): [A(t)4, B(t+1)c0..c3 (2 each)]
//   ph0: vmcnt(6)  drains A(t)+c0 ;  ph1..3: vmcnt(10) drains c1/c2/c3.
// Prologue reproduces the queue; tail issues clamped-unconditional.
template<int K, int N, int NY>
__global__ __launch_bounds__(512) void k_gemm1(
    const u16* __restrict__ A, const float* __restrict__ Bf, u16* __restrict__ C,
    const int4* __restrict__ map, const int* __restrict__ nblocks)
{
  const int mblk = (int)blockIdx.x / NY;
  const int nblk = (int)blockIdx.x % NY;
  if (mblk >= *nblocks) return;
  const int4 mi = map[mblk];
  const int e = mi.x, row0 = mi.y, rowend = mi.z;
  const int n0 = nblk << 8;
  const int NT = K / 64;                      // 16

  __shared__ __align__(16) u16 sa[2][256 * 64];   // 64KB, swizzled chunks
  __shared__ __align__(16) u16 sb[2][256 * 72];   // 72KB, 144B pitch

  const int tid = threadIdx.x;
  const int wid = tid >> 6, lane = tid & 63;
  const int wr = wid >> 2, wc = wid & 3;      // 2 M-halves x 4 N-quarters
  const int fr = lane & 15, fq = lane >> 4;

  f32x4 acc[8][4];
#pragma unroll
  for (int m = 0; m < 8; ++m)
#pragma unroll
    for (int n = 0; n < 4; ++n) acc[m][n] = (f32x4)0.f;

  const float* B = Bf + (size_t)e * ((size_t)N * K);

  float4 rb[2][8];                  // 2 sets x 8 float4 (one tile of B each)

  auto issueA = [&](int t, int buf) {   // 4 gload_lds, chunk-swizzled source
#pragma unroll
    for (int i = 0; i < 4; ++i) {
      int slot = i * 512 + tid;                 // r=slot>>3 (0..255), j=slot&7
      int r = slot >> 3, j = slot & 7;
      int cs = j ^ (r & 7);
      int row = row0 + r;
      row = row < TDIM ? row : TDIM - 1;
      const u16* g = A + (size_t)row * K + t * 64 + cs * 8;
      __builtin_amdgcn_global_load_lds(
          (const __attribute__((address_space(1))) u32*)g,
          (__attribute__((address_space(3))) u32*)(&sa[buf][slot * 8]),
          16, 0, 0);
    }
  };
  auto loadBc = [&](int t, int c, auto ic) {    // chunk c: 2 float4, rows [c*64,c*64+64)
    constexpr int S = decltype(ic)::v;
#pragma unroll
    for (int i = 0; i < 2; ++i) {
      int local = i * 512 + tid;                // 0..1023: n=c*64+(local>>4), f4=local&15
      rb[S][c * 2 + i] = *(const float4*)(
          B + (size_t)(n0 + c * 64 + (local >> 4)) * K + t * 64 + (local & 15) * 4);
    }
  };
  auto writeBc = [&](int buf, int c, auto ic) {
    constexpr int S = decltype(ic)::v;
#pragma unroll
    for (int i = 0; i < 2; ++i) {
      int local = i * 512 + tid;
      int n = c * 64 + (local >> 4), f4 = local & 15;
      float4 v = rb[S][c * 2 + i];
      uint2 o;
      o.x = pk2(v.x, v.y);
      o.y = pk2(v.z, v.w);
      *(uint2*)(&sb[buf][n * 72 + f4 * 4]) = o;   // byte n*144 + f4*8
    }
  };
  auto readA = [&](short8* av, int buf, int mh, int ks) {
#pragma unroll
    for (int i = 0; i < 4; ++i) {
      int R = wr * 128 + (mh * 4 + i) * 16 + fr;
      av[i] = *(const short8*)(&sa[buf][R * 64 + (((ks * 4 + fq) ^ (R & 7)) * 8)]);
    }
  };
  auto readB = [&](short8* bv, int buf, int ks) {
#pragma unroll
    for (int n = 0; n < 4; ++n) {
      int R = wc * 64 + n * 16 + fr;
      bv[n] = *(const short8*)(&sb[buf][R * 72 + ks * 32 + fq * 8]);
    }
  };

  auto tile = [&](int t, auto icW, auto icL) {  // icW: set holding B(t+1); icL: load B(t+2)
    const int cur = t & 1, nxt = cur ^ 1;
    const int tA = (t + 1 < NT) ? (t + 1) : (NT - 1);
    const int tB = (t + 2 < NT) ? (t + 2) : (NT - 1);
    short8 av[4], bv[4];
    // ---- phase 0: mh0, ks0 ----
    waitv<6>();
    readA(av, cur, 0, 0);
    readB(bv, cur, 0);
    issueA(tA, nxt);
    loadBc(tB, 0, icL);
    writeBc(nxt, 0, icW);
    __builtin_amdgcn_s_barrier();
    waitl();
    __builtin_amdgcn_s_setprio(1);
#pragma unroll
    for (int i = 0; i < 4; ++i)
#pragma unroll
      for (int n = 0; n < 4; ++n)
        acc[i][n] = __builtin_amdgcn_mfma_f32_16x16x32_bf16(av[i], bv[n], acc[i][n], 0, 0, 0);
    __builtin_amdgcn_s_setprio(0);
    __builtin_amdgcn_s_barrier();
    // ---- phase 1: mh1, ks0 ----
    waitv<10>();
    readA(av, cur, 1, 0);
    loadBc(tB, 1, icL);
    writeBc(nxt, 1, icW);
    __builtin_amdgcn_s_barrier();
    waitl();
    __builtin_amdgcn_s_setprio(1);
#pragma unroll
    for (int i = 0; i < 4; ++i)
#pragma unroll
      for (int n = 0; n < 4; ++n)
        acc[4 + i][n] = __builtin_amdgcn_mfma_f32_16x16x32_bf16(av[i], bv[n], acc[4 + i][n], 0, 0, 0);
    __builtin_amdgcn_s_setprio(0);
    __builtin_amdgcn_s_barrier();
    // ---- phase 2: mh0, ks1 ----
    waitv<10>();
    readA(av, cur, 0, 1);
    readB(bv, cur, 1);
    loadBc(tB, 2, icL);
    writeBc(nxt, 2, icW);
    __builtin_amdgcn_s_barrier();
    waitl();
    __builtin_amdgcn_s_setprio(1);
#pragma unroll
    for (int i = 0; i < 4; ++i)
#pragma unroll
      for (int n = 0; n < 4; ++n)
        acc[i][n] = __builtin_amdgcn_mfma_f32_16x16x32_bf16(av[i], bv[n], acc[i][n], 0, 0, 0);
    __builtin_amdgcn_s_setprio(0);
    __builtin_amdgcn_s_barrier();
    // ---- phase 3: mh1, ks1 ----
    waitv<10>();
    readA(av, cur, 1, 1);
    loadBc(tB, 3, icL);
    writeBc(nxt, 3, icW);
    __builtin_amdgcn_s_barrier();
    waitl();
    __builtin_amdgcn_s_setprio(1);
#pragma unroll
    for (int i = 0; i < 4; ++i)
#pragma unroll
      for (int n = 0; n < 4; ++n)
        acc[4 + i][n] = __builtin_amdgcn_mfma_f32_16x16x32_bf16(av[i], bv[n], acc[4 + i][n], 0, 0, 0);
    __builtin_amdgcn_s_setprio(0);
    __builtin_amdgcn_s_barrier();
  };

  // prologue: queue ends as [A(0)x4, B(1)x8] with sb[0] <- B(0)
  loadBc(0, 0, IC0{}); loadBc(0, 1, IC0{}); loadBc(0, 2, IC0{}); loadBc(0, 3, IC0{});
  issueA(0, 0);
  waitv<4>();                        // drain B(0), leave A(0)
  writeBc(0, 0, IC0{}); writeBc(0, 1, IC0{}); writeBc(0, 2, IC0{}); writeBc(0, 3, IC0{});
  loadBc(1, 0, IC1{}); loadBc(1, 1, IC1{}); loadBc(1, 2, IC1{}); loadBc(1, 3, IC1{});
  waitl();
  __builtin_amdgcn_s_barrier();      // publish sb[0]

  for (int t = 0; t < NT; t += 2) {
    tile(t,     IC1{}, IC0{});       // writes B(t+1) from set1, loads B(t+2) into set0
    tile(t + 1, IC0{}, IC1{});
  }

  // epilogue: gelu(tanh) + bf16;  C/D layout row=(lane>>4)*4+j, col=lane&15
#pragma unroll
  for (int m = 0; m < 8; ++m) {
    const int rb_ = row0 + wr * 128 + m * 16 + fq * 4;
#pragma unroll
    for (int n = 0; n < 4; ++n) {
      const int col = n0 + wc * 64 + n * 16 + fr;
#pragma unroll
      for (int j = 0; j < 4; ++j) {
        int r = rb_ + j;
        if (r < rowend) C[(size_t)r * N + col] = f2bf(gelu_tanh(acc[m][n][j]));
      }
    }
  }
}

// ======================= GEMM2: out = h @ w2 =======================
// Same phase discipline at BK=32, 2 phases/tile (VGPR-safe for the n-contig
// B path). 256x256 tile, 8 waves 2Mx4N, acc[8][4].
// A: bf16 gload_lds sa[2] [256][32] (chunk-swz (r>>1)&3, proven), 2 issues/tile (ph0).
// B: w2 f32 [K][N]: thread owns (n=tid&255, h=tid>>8), 16 scalars/tile in 2
//    chunks of 8 (1/phase) -> pk2 -> b128 ds_write into sb[2] [256][40] (80B pitch).
// Steady queue at tile t ph0: [A(t)2, B(t+1)c0(8), c1(8)]
//   ph0: vmcnt(8) drains A(t)+c0 ; ph1: vmcnt(10) drains c1.
template<int K, int N, int NY>
__global__ __launch_bounds__(512) void k_gemm2(
    const u16* __restrict__ A, const float* __restrict__ Bf, float* __restrict__ C,
    const int4* __restrict__ map, const int* __restrict__ nblocks)
{
  const int mblk = (int)blockIdx.x / NY;
  const int nblk = (int)blockIdx.x % NY;
  if (mblk >= *nblocks) return;
  const int4 mi = map[mblk];
  const int e = mi.x, row0 = mi.y, rowend = mi.z;
  const int n0 = nblk << 8;
  const int NT = K / 32;                      // 64

  __shared__ __align__(16) u16 sa[2][256 * 32];   // 32KB
  __shared__ __align__(16) u16 sb[2][256 * 40];   // 40KB, 80B pitch

  const int tid = threadIdx.x;
  const int wid = tid >> 6, lane = tid & 63;
  const int wr = wid >> 2, wc = wid & 3;
  const int fr = lane & 15, fq = lane >> 4;

  f32x4 acc[8][4];
#pragma unroll
  for (int m = 0; m < 8; ++m)
#pragma unroll
    for (int n = 0; n < 4; ++n) acc[m][n] = (f32x4)0.f;

  const float* B = Bf + (size_t)e * ((size_t)N * K);

  float rb[2][16];                  // 2 sets x (2 chunks x 8 scalars)
  const int bn = tid & 255;
  const int bh = tid >> 8;          // 0,1: k-half of 16

  auto issueA = [&](int t, int buf) {   // 2 gload_lds
#pragma unroll
    for (int i = 0; i < 2; ++i) {
      int slot = i * 512 + tid;                 // r=slot>>2 (0..255), j=slot&3
      int r = slot >> 2, j = slot & 3;
      int cs = j ^ ((r >> 1) & 3);
      int row = row0 + r;
      row = row < TDIM ? row : TDIM - 1;
      const u16* g = A + (size_t)row * K + t * 32 + cs * 8;
      __builtin_amdgcn_global_load_lds(
          (const __attribute__((address_space(1))) u32*)g,
          (__attribute__((address_space(3))) u32*)(&sa[buf][slot * 8]),
          16, 0, 0);
    }
  };
  auto loadBc = [&](int t, int c, auto ic) {    // chunk c: 8 scalars, k = bh*16+c*8+j
    constexpr int S = decltype(ic)::v;
    const float* src = B + (size_t)(t * 32 + bh * 16 + c * 8) * N + n0 + bn;
#pragma unroll
    for (int j = 0; j < 8; ++j) rb[S][c * 8 + j] = src[(size_t)j * N];
  };
  auto writeBc = [&](int buf, int c, auto ic) {
    constexpr int S = decltype(ic)::v;
    uint4 o;
    o.x = pk2(rb[S][c * 8 + 0], rb[S][c * 8 + 1]);
    o.y = pk2(rb[S][c * 8 + 2], rb[S][c * 8 + 3]);
    o.z = pk2(rb[S][c * 8 + 4], rb[S][c * 8 + 5]);
    o.w = pk2(rb[S][c * 8 + 6], rb[S][c * 8 + 7]);
    *(uint4*)(&sb[buf][bn * 40 + bh * 16 + c * 8]) = o;   // byte bn*80+bh*32+c*16
  };
  auto readA = [&](short8* av, int buf, int mh) {
#pragma unroll
    for (int i = 0; i < 4; ++i) {
      int R = wr * 128 + (mh * 4 + i) * 16 + fr;
      av[i] = *(const short8*)(&sa[buf][R * 32 + ((fq ^ ((R >> 1) & 3)) * 8)]);
    }
  };

  auto tile = [&](int t, auto icW, auto icL) {
    const int cur = t & 1, nxt = cur ^ 1;
    const int tA = (t + 1 < NT) ? (t + 1) : (NT - 1);
    const int tB = (t + 2 < NT) ? (t + 2) : (NT - 1);
    short8 av[4], bv[4];
    // ---- phase 0: mh0 ----
    waitv<8>();
    readA(av, cur, 0);
#pragma unroll
    for (int n = 0; n < 4; ++n) {
      int R = wc * 64 + n * 16 + fr;
      bv[n] = *(const short8*)(&sb[cur][R * 40 + fq * 8]);
    }
    issueA(tA, nxt);
    loadBc(tB, 0, icL);
    writeBc(nxt, 0, icW);
    __builtin_amdgcn_s_barrier();
    waitl();
    __builtin_amdgcn_s_setprio(1);
#pragma unroll
    for (int i = 0; i < 4; ++i)
#pragma unroll
      for (int n = 0; n < 4; ++n)
        acc[i][n] = __builtin_amdgcn_mfma_f32_16x16x32_bf16(av[i], bv[n], acc[i][n], 0, 0, 0);
    __builtin_amdgcn_s_setprio(0);
    __builtin_amdgcn_s_barrier();
    // ---- phase 1: mh1 ----
    waitv<10>();
    readA(av, cur, 1);
    loadBc(tB, 1, icL);
    writeBc(nxt, 1, icW);
    __builtin_amdgcn_s_barrier();
    waitl();
    __builtin_amdgcn_s_setprio(1);
#pragma unroll
    for (int i = 0; i < 4; ++i)
#pragma unroll
      for (int n = 0; n < 4; ++n)
        acc[4 + i][n] = __builtin_amdgcn_mfma_f32_16x16x32_bf16(av[i], bv[n], acc[4 + i][n], 0, 0, 0);
    __builtin_amdgcn_s_setprio(0);
    __builtin_amdgcn_s_barrier();
  };

  // prologue: queue ends as [A(0)x2, B(1)x16] with sb[0] <- B(0)
  loadBc(0, 0, IC0{}); loadBc(0, 1, IC0{});
  issueA(0, 0);
  waitv<2>();                        // drain B(0), leave A(0)
  writeBc(0, 0, IC0{}); writeBc(0, 1, IC0{});
  loadBc(1, 0, IC1{}); loadBc(1, 1, IC1{});
  waitl();
  __builtin_amdgcn_s_barrier();      // publish sb[0]

  for (int t = 0; t < NT; t += 2) {
    tile(t,     IC1{}, IC0{});
    tile(t + 1, IC0{}, IC1{});
  }

#pragma unroll
  for (int m = 0; m < 8; ++m) {
    const int rb_ = row0 + wr * 128 + m * 16 + fq * 4;
#pragma unroll
    for (int n = 0; n < 4; ++n) {
      const int col = n0 + wc * 64 + n * 16 + fr;
#pragma unroll
      for (int j = 0; j < 4; ++j) {
        int r = rb_ + j;
        if (r < rowend) C[(size_t)r * N + col] = acc[m][n][j];
      }
    }
  }
}

extern "C" void kernel_launch(void* const* d_in, const int* in_sizes, int n_in,
                              void* d_out, int out_size, void* d_ws, size_t ws_size,
                              hipStream_t stream) {
  const float* x  = (const float*)d_in[0];
  const float* w1 = (const float*)d_in[1];
  const float* w2 = (const float*)d_in[2];
  const int*  tpe = (const int*)d_in[3];

  char* ws = (char*)d_ws;
  int4* map     = (int4*)ws;
  int*  nblocks = (int*)(ws + 4096);
  u16*  xb      = (u16*)(ws + 8192);               // T*H bf16 = 32MB
  u16*  hb      = xb + (size_t)TDIM * HDIM;        // T*F bf16 = 64MB

  k_prep<<<1, 64, 0, stream>>>(tpe, map, nblocks);
  k_conv<<<2048, 256, 0, stream>>>((const float4*)x, (uint2*)xb, (TDIM * HDIM) / 4);
  // GEMM1: B=w1 f32 [F][H]=[N][K] k-contig; BN=256 -> NY=8
  k_gemm1<HDIM, FDIM, 8><<<128 * 8, 512, 0, stream>>>(
      xb, w1, hb, map, nblocks);
  // GEMM2: B=w2 f32 [F][H]=[K][N] n-contig; BN=256 -> NY=4
  k_gemm2<FDIM, HDIM, 4><<<128 * 4, 512, 0, stream>>>(
      hb, w2, (float*)d_out, map, nblocks);
}

// Round 17
// 471.033 us; speedup vs baseline: 1.1441x; 1.1441x over previous
//
#include <hip/hip_runtime.h>
#include <hip/hip_bf16.h>

#define NE 64
#define HDIM 1024
#define FDIM 2048
#define TDIM 16384

typedef __attribute__((ext_vector_type(8))) short short8;
typedef __attribute__((ext_vector_type(4))) float f32x4;
typedef unsigned short u16;
typedef unsigned int u32;

struct IC0 { static constexpr int v = 0; };
struct IC1 { static constexpr int v = 1; };
template<int W> struct WN { static constexpr int v = W; };

__device__ __forceinline__ u16 f2bf(float f) {
  return __bfloat16_as_ushort(__float2bfloat16(f));
}
__device__ __forceinline__ u32 pk2(float a, float b) {
  return (u32)f2bf(a) | ((u32)f2bf(b) << 16);
}
template<int N> __device__ __forceinline__ void waitv() {
  if constexpr (N == 2)       asm volatile("s_waitcnt vmcnt(2)" ::: "memory");
  else if constexpr (N == 4)  asm volatile("s_waitcnt vmcnt(4)" ::: "memory");
  else if constexpr (N == 8)  asm volatile("s_waitcnt vmcnt(8)" ::: "memory");
  else if constexpr (N == 10) asm volatile("s_waitcnt vmcnt(10)" ::: "memory");
}
__device__ __forceinline__ void waitl() {
  asm volatile("s_waitcnt lgkmcnt(0)" ::: "memory");
}

// ---- prep: build M-block map (expert, row0, rowend), BM=256 ----
__global__ void k_prep(const int* __restrict__ tpe, int4* __restrict__ map,
                       int* __restrict__ nblocks) {
  if (threadIdx.x != 0 || blockIdx.x != 0) return;
  int off = 0, nb = 0;
  for (int e = 0; e < NE; ++e) {
    int n = tpe[e];
    for (int r = 0; r < n; r += 256) {
      int re = (r + 256 < n) ? (r + 256) : n;
      map[nb++] = make_int4(e, off + r, off + re, 0);
    }
    off += n;
  }
  *nblocks = nb;
}

// ---- f32 -> bf16 convert ----
__global__ void k_conv(const float4* __restrict__ in, uint2* __restrict__ out, int n4) {
  int stride = gridDim.x * blockDim.x;
  for (int i = blockIdx.x * blockDim.x + threadIdx.x; i < n4; i += stride) {
    float4 v = in[i];
    uint2 o;
    o.x = pk2(v.x, v.y);
    o.y = pk2(v.z, v.w);
    out[i] = o;
  }
}

// ---- grouped GEMM: 256x128 tile, BK=32, 512 threads (8 waves of 64x64).
// ONE s_barrier per K-step; counted vmcnt keeps loads in flight across it.
// A: bf16, gload_lds, 3-deep LDS rotation -> TRUE 2-body flight
//    (body(t) reads sa[t%3], issues A(t+2) into sa[(t+2)%3] — never a buffer
//    read this or next body). XOR-swizzled source chunk c^((r>>1)&3), same
//    XOR on frag read -> conflict-free ds_read_b128.
// B: f32 w, 2-body reg flight (ping-pong sets, static idx), cvt+ds_write into
//    LDS dbuf (80B rows: conflict-free).
// Steady top-of-body(t) outstanding, age order:
//   A(t)[2], B(t+1)[LB], A(t+1)[2], B(t+2)[LB]
//   -> vmcnt(2+LB) drains exactly A(t)+B(t+1).  body(0) peeled: vmcnt(LB)
//   (drains A(1) early — harmless).  Tail: unconditional clamped dummy issues
//   keep the in-flight pattern invariant (round-7 race fix).
//   BMODE==1: B [N][K] k-contig  -> 2x float4/thread   (LB=2)
//   BMODE==2: B [K][N] n-contig  -> 8x f32/thread      (LB=8)
template<int K, int N, bool GELU, int BMODE, int NY>
__global__ __launch_bounds__(512) void k_gemm(
    const u16* __restrict__ A, const float* __restrict__ Bf, void* __restrict__ C,
    const int4* __restrict__ map, const int* __restrict__ nblocks)
{
  const int mblk = (int)blockIdx.x / NY;
  const int nblk = (int)blockIdx.x % NY;
  if (mblk >= *nblocks) return;
  const int4 mi = map[mblk];
  const int e = mi.x, row0 = mi.y, rowend = mi.z;
  const int n0 = nblk << 7;
  const int NT = K / 32;                      // 32 or 64, even
  constexpr int LB = (BMODE == 1) ? 2 : 8;    // B vmem ops per body per thread

  __shared__ __align__(16) u16 sa[3][8192];     // A [256][32] (swizzled), 3-rot
  __shared__ __align__(16) u16 sb[2][128 * 40]; // B [128 n][40], dbuf

  const int tid = threadIdx.x;
  const int wid = tid >> 6, lane = tid & 63;
  const int wr = wid >> 1, wc = wid & 1;      // 4 row-quads x 2 col-halves
  const int fr = lane & 15, fq = lane >> 4;

  f32x4 acc[4][4];
#pragma unroll
  for (int m = 0; m < 4; ++m)
#pragma unroll
    for (int n = 0; n < 4; ++n) acc[m][n] = (f32x4)0.f;

  const float* B = Bf + (size_t)e * ((size_t)N * K);

  float4 rb1[2][2];                 // BMODE1 ping-pong reg sets
  float  rb2[2][8];                 // BMODE2 ping-pong reg sets
  const int bn  = tid & 127;        // BMODE2: owned n-column
  const int oct = tid >> 7;         // BMODE2: k-octet (0..3)

  auto issueA = [&](int t, int buf) {
#pragma unroll
    for (int i = 0; i < 2; ++i) {
      int slot = i * 512 + tid;                 // row=slot>>2, chunk=slot&3
      int r = slot >> 2, c = slot & 3;
      int cs = c ^ ((r >> 1) & 3);              // pre-swizzled source chunk
      int row = row0 + r;
      row = row < TDIM ? row : TDIM - 1;
      const u16* g = A + (size_t)row * K + t * 32 + cs * 8;
      __builtin_amdgcn_global_load_lds(
          (const __attribute__((address_space(1))) u32*)g,
          (__attribute__((address_space(3))) u32*)(&sa[buf][i * 4096 + wid * 512]),
          16, 0, 0);
    }
  };
  auto loadB = [&](int t, auto ic) {
    constexpr int S = decltype(ic)::v;
    if constexpr (BMODE == 1) {
#pragma unroll
      for (int i = 0; i < 2; ++i) {
        int slot = i * 512 + tid;               // n=slot>>3, k16=slot&7
        rb1[S][i] = *(const float4*)(B + (size_t)(n0 + (slot >> 3)) * K + t * 32 + (slot & 7) * 4);
      }
    } else {
      const float* src = B + (size_t)(t * 32 + oct * 8) * N + n0 + bn;
#pragma unroll
      for (int i = 0; i < 8; ++i) rb2[S][i] = src[(size_t)i * N];
    }
  };
  auto writeB = [&](int buf, auto ic) {
    constexpr int S = decltype(ic)::v;
    if constexpr (BMODE == 1) {
#pragma unroll
      for (int i = 0; i < 2; ++i) {
        int slot = i * 512 + tid;
        uint2 o;
        o.x = pk2(rb1[S][i].x, rb1[S][i].y);
        o.y = pk2(rb1[S][i].z, rb1[S][i].w);
        *(uint2*)(&sb[buf][(slot >> 3) * 40 + (slot & 7) * 4]) = o;
      }
    } else {
      uint4 c;
      c.x = pk2(rb2[S][0], rb2[S][1]); c.y = pk2(rb2[S][2], rb2[S][3]);
      c.z = pk2(rb2[S][4], rb2[S][5]); c.w = pk2(rb2[S][6], rb2[S][7]);
      *(uint4*)(&sb[buf][bn * 40 + oct * 8]) = c;   // byte bn*80+oct*16 (80=5x16)
    }
  };

  auto body = [&](int t, auto icCur, auto wn) {
    waitv<decltype(wn)::v>();  // steady: drains A(t)+B(t+1)
    waitl();                   // own ds_writes from prev body drained
    __builtin_amdgcn_s_barrier();
    const int cur3 = t % 3, curb = t & 1, nxtb = curb ^ 1;
    short8 av[4], bv[4];
#pragma unroll
    for (int m = 0; m < 4; ++m) {
      const int row = wr * 64 + m * 16 + fr;
      av[m] = *(const short8*)(&sa[cur3][row * 32 + (fq ^ ((row >> 1) & 3)) * 8]);
    }
#pragma unroll
    for (int n = 0; n < 4; ++n)
      bv[n] = *(const short8*)(&sb[curb][(wc * 64 + n * 16 + fr) * 40 + fq * 8]);
    // UNCONDITIONAL issues; tile index clamped at tail, buffers keep rotating.
    issueA((t + 2 < NT) ? (t + 2) : (NT - 1), (t + 2) % 3);
    writeB(nxtb, icCur);                               // sb[nxt] <- B(t+1) regs
    loadB((t + 3 < NT) ? (t + 3) : (NT - 1), icCur);   // refill same reg set
#pragma unroll
    for (int m = 0; m < 4; ++m)
#pragma unroll
      for (int n = 0; n < 4; ++n)
        acc[m][n] = __builtin_amdgcn_mfma_f32_16x16x32_bf16(av[m], bv[n], acc[m][n], 0, 0, 0);
  };

  // prologue (order matters for vmcnt age accounting):
  issueA(0, 0);         // A(0) -> sa[0]
  loadB(0, IC0{});      // B(0) -> set0
  issueA(1, 1);         // A(1) -> sa[1]
  loadB(1, IC1{});      // B(1) -> set1
  waitv<2 + LB>();      // drains A(0)+B(0); leaves A(1),B(1)
  writeB(0, IC0{});     // sb[0] <- B(0)
  loadB(2, IC0{});      // B(2) -> set0
  // outstanding: A(1)[2], B(1)[LB], B(2)[LB]

  body(0, IC1{}, WN<LB>{});       // drains A(1)(early)+B(1); leaves B(2)
  body(1, IC0{}, WN<2 + LB>{});   // drains B(2); leaves A(2),B(3)
  for (int t = 2; t < NT; t += 2) {
    body(t,     IC1{}, WN<2 + LB>{});
    body(t + 1, IC0{}, WN<2 + LB>{});
  }

  // epilogue: C/D layout row=(lane>>4)*4+j, col=lane&15
#pragma unroll
  for (int m = 0; m < 4; ++m) {
    const int rb = row0 + wr * 64 + m * 16 + fq * 4;
#pragma unroll
    for (int n = 0; n < 4; ++n) {
      const int col = n0 + wc * 64 + n * 16 + fr;
#pragma unroll
      for (int j = 0; j < 4; ++j) {
        int r = rb + j;
        if (r < rowend) {
          float vv = acc[m][n][j];
          if constexpr (GELU) {
            vv = 0.5f * vv * (1.f + erff(vv * 0.70710678118654752f));
            ((u16*)C)[(size_t)r * N + col] = f2bf(vv);
          } else {
            ((float*)C)[(size_t)r * N + col] = vv;
          }
        }
      }
    }
  }
}

extern "C" void kernel_launch(void* const* d_in, const int* in_sizes, int n_in,
                              void* d_out, int out_size, void* d_ws, size_t ws_size,
                              hipStream_t stream) {
  const float* x  = (const float*)d_in[0];
  const float* w1 = (const float*)d_in[1];
  const float* w2 = (const float*)d_in[2];
  const int*  tpe = (const int*)d_in[3];

  char* ws = (char*)d_ws;
  int4* map     = (int4*)ws;                       // up to 256 entries
  int*  nblocks = (int*)(ws + 4096);
  u16*  xb      = (u16*)(ws + 8192);               // T*H bf16 = 32MB
  u16*  hb      = xb + (size_t)TDIM * HDIM;        // T*F bf16 = 64MB

  k_prep<<<1, 64, 0, stream>>>(tpe, map, nblocks);
  k_conv<<<2048, 256, 0, stream>>>((const float4*)x, (uint2*)xb, (TDIM * HDIM) / 4);
  // GEMM1: h = gelu(x @ w1^T)   B=w1 f32 [F][H] = [N][K], NY=16
  k_gemm<HDIM, FDIM, true,  1, 16><<<128 * 16, 512, 0, stream>>>(
      xb, w1, (void*)hb, map, nblocks);
  // GEMM2: out = h @ w2         B=w2 f32 [F][H] = [K][N], NY=8
  k_gemm<FDIM, HDIM, false, 2, 8><<<128 * 8, 512, 0, stream>>>(
      hb, w2, d_out, map, nblocks);
}